// Round 1
// baseline (445.749 us; speedup 1.0000x reference)
//
#include <hip/hip_runtime.h>

#define N 8192
#define D 128
#define ALPHA 0.2f
#define CAP 1536   // max nonzeros per row we can hold; Binomial(8191,0.01)+1 maxes ~140

// ---------------------------------------------------------------------------
// Kernel 1: H = X @ W^T + b ; s = H @ a_s ; r = H @ a_r
// grid 256 blocks x 256 threads; each block computes 32 rows x 128 cols.
// LDS: X tile transposed (k-major) + half-K W tile (k-major) = ~52 KB.
// Each thread: 4 rows x 4 cols register tile; float4 LDS reads.
// ---------------------------------------------------------------------------
__global__ __launch_bounds__(256) void linear_kernel(
    const float* __restrict__ X, const float* __restrict__ W,
    const float* __restrict__ b, const float* __restrict__ a_s,
    const float* __restrict__ a_r,
    float* __restrict__ H, float* __restrict__ sv, float* __restrict__ rv)
{
    __shared__ float Xs[128 * 36];   // Xs[k*36 + row], pad 36 keeps float4 align + no write conflicts worth caring about
    __shared__ float Ws[64 * 132];   // Ws[kk*132 + o]  (k-major, o contiguous for float4 reads)

    const int tid = threadIdx.x;
    const int i0  = blockIdx.x * 32;

    // stage X tile transposed: global coalesced read, LDS write (4-way conflict, tiny)
    for (int idx = tid; idx < 32 * 128; idx += 256) {
        const int row = idx >> 7, k = idx & 127;
        Xs[k * 36 + row] = X[(i0 + row) * D + k];
    }

    float acc[4][4] = {};
    const int ty = tid >> 5, tx = tid & 31;
    const int rbase = ty * 4, cbase = tx * 4;

    for (int kb = 0; kb < 2; ++kb) {
        __syncthreads();   // Xs ready (kb=0) / all Ws reads done (kb=1)
        for (int idx = tid; idx < 64 * 128; idx += 256) {
            const int o = idx >> 6, kk = idx & 63;
            Ws[kk * 132 + o] = W[o * D + kb * 64 + kk];
        }
        __syncthreads();
        #pragma unroll
        for (int kk = 0; kk < 64; ++kk) {
            const float4 xv = *(const float4*)&Xs[(kb * 64 + kk) * 36 + rbase];
            const float4 wv = *(const float4*)&Ws[kk * 132 + cbase];
            const float xr[4] = {xv.x, xv.y, xv.z, xv.w};
            const float wc[4] = {wv.x, wv.y, wv.z, wv.w};
            #pragma unroll
            for (int r = 0; r < 4; ++r)
                #pragma unroll
                for (int c = 0; c < 4; ++c)
                    acc[r][c] += xr[r] * wc[c];
        }
    }

    // epilogue: +b, store H, and reduce s/r across the 32 tx lanes
    const float4 bv  = *(const float4*)&b[cbase];
    const float4 asv = *(const float4*)&a_s[cbase];
    const float4 arv = *(const float4*)&a_r[cbase];
    #pragma unroll
    for (int r = 0; r < 4; ++r) {
        float4 h;
        h.x = acc[r][0] + bv.x;
        h.y = acc[r][1] + bv.y;
        h.z = acc[r][2] + bv.z;
        h.w = acc[r][3] + bv.w;
        *(float4*)&H[(size_t)(i0 + rbase + r) * D + cbase] = h;
        float ps = h.x * asv.x + h.y * asv.y + h.z * asv.z + h.w * asv.w;
        float pr = h.x * arv.x + h.y * arv.y + h.z * arv.z + h.w * arv.w;
        #pragma unroll
        for (int off = 16; off > 0; off >>= 1) {
            ps += __shfl_xor(ps, off);
            pr += __shfl_xor(pr, off);
        }
        if (tx == 0) {
            sv[i0 + rbase + r] = ps;
            rv[i0 + rbase + r] = pr;
        }
    }
}

// ---------------------------------------------------------------------------
// Kernel 2: per-row sparse softmax-attention. One block (256 thr) per row.
// Scan A[i,:] (float4, HBM streaming), collect nonzeros into LDS list,
// block max -> exp/sum -> weighted gather of H rows (L2/L3-resident).
// ---------------------------------------------------------------------------
__global__ __launch_bounds__(256) void attn_kernel(
    const float* __restrict__ A, const float* __restrict__ H,
    const float* __restrict__ sv, const float* __restrict__ rv,
    float* __restrict__ out)
{
    __shared__ int   s_idx[CAP];
    __shared__ float s_z[CAP];
    __shared__ int   s_cnt;
    __shared__ float s_redm[4];
    __shared__ float s_reds[4];
    __shared__ float s_hbuf[128];

    const int tid = threadIdx.x;
    const int i   = blockIdx.x;
    if (tid == 0) s_cnt = 0;
    __syncthreads();

    const float  si   = sv[i];
    const float4* Arow = (const float4*)(A + (size_t)i * N);

    float lm = -3.0e38f;
    #pragma unroll
    for (int it = 0; it < 8; ++it) {
        const int idx4 = it * 256 + tid;
        const float4 a = Arow[idx4];
        const float av[4] = {a.x, a.y, a.z, a.w};
        #pragma unroll
        for (int e = 0; e < 4; ++e) {
            if (av[e] != 0.0f) {
                const int j = idx4 * 4 + e;
                float z = si + rv[j];
                z = (z > 0.0f) ? z : ALPHA * z;   // leaky_relu
                const int p = atomicAdd(&s_cnt, 1);
                if (p < CAP) { s_idx[p] = j; s_z[p] = z; }
                lm = fmaxf(lm, z);
            }
        }
    }

    // block max
    #pragma unroll
    for (int off = 32; off > 0; off >>= 1) lm = fmaxf(lm, __shfl_xor(lm, off));
    if ((tid & 63) == 0) s_redm[tid >> 6] = lm;
    __syncthreads();
    const int   cnt = (s_cnt < CAP) ? s_cnt : CAP;
    const float m   = fmaxf(fmaxf(s_redm[0], s_redm[1]), fmaxf(s_redm[2], s_redm[3]));

    // exp + sum (in-place overwrite z -> w)
    float sl = 0.0f;
    for (int p = tid; p < cnt; p += 256) {
        const float w = __expf(s_z[p] - m);
        s_z[p] = w;
        sl += w;
    }
    #pragma unroll
    for (int off = 32; off > 0; off >>= 1) sl += __shfl_xor(sl, off);
    if ((tid & 63) == 0) s_reds[tid >> 6] = sl;
    __syncthreads();
    const float inv = 1.0f / (s_reds[0] + s_reds[1] + s_reds[2] + s_reds[3]);

    // weighted accumulate: 128 feature threads x 2 halves of the nnz list
    const int d = tid & 127, half = tid >> 7;
    float acc = 0.0f;
    for (int p = half; p < cnt; p += 2)
        acc += s_z[p] * H[(size_t)s_idx[p] * D + d];

    if (half == 1) s_hbuf[d] = acc;
    __syncthreads();
    if (half == 0) out[(size_t)i * D + d] = (acc + s_hbuf[d]) * inv;
}

extern "C" void kernel_launch(void* const* d_in, const int* in_sizes, int n_in,
                              void* d_out, int out_size, void* d_ws, size_t ws_size,
                              hipStream_t stream) {
    const float* X   = (const float*)d_in[0];
    const float* A   = (const float*)d_in[1];
    const float* W   = (const float*)d_in[2];
    const float* b   = (const float*)d_in[3];
    const float* a_s = (const float*)d_in[4];
    const float* a_r = (const float*)d_in[5];
    float* out = (float*)d_out;

    float* H  = (float*)d_ws;               // N*D floats = 4 MB
    float* sv = H + (size_t)N * D;          // N floats
    float* rv = sv + N;                     // N floats

    linear_kernel<<<256, 256, 0, stream>>>(X, W, b, a_s, a_r, H, sv, rv);
    attn_kernel<<<N, 256, 0, stream>>>(A, H, sv, rv, out);
}